// Round 1
// baseline (100.529 us; speedup 1.0000x reference)
//
#include <hip/hip_runtime.h>
#include <hip/hip_bf16.h>
#include <math.h>

#define BT    1024
#define NWAVE (BT / 64)
#define NROW  100
#define DDIM  768
#define EPS_LN 1e-5f
#define EPSF   1e-8f

// LDS layout (bytes):
//   u    : [100][768] ushort (bf16)  -> 153600
//   S    : [768] float               ->   3072   @153600
//   nrm  : [100] float               ->    400   @156672
//   dens : [100] float               ->    400   @157072
//   w2   : [100] float               ->    400   @157472
//   Wsh  : [1] float                 ->      4   @157872
#define LDS_BYTES 157888

__device__ __forceinline__ unsigned short f2bf(float f) {
    union { float f; unsigned int u; } c; c.f = f;
    unsigned int u = c.u;
    unsigned int r = (u + 0x7FFFu + ((u >> 16) & 1u)) >> 16;
    return (unsigned short)r;
}
__device__ __forceinline__ float bf2f(unsigned short h) {
    union { unsigned int u; float f; } c; c.u = ((unsigned int)h) << 16;
    return c.f;
}

__device__ __forceinline__ float wave_sum(float v) {
#pragma unroll
    for (int m = 32; m >= 1; m >>= 1) v += __shfl_xor(v, m, 64);
    return v;
}

extern "C" __global__ void __launch_bounds__(BT, 1)
ccs_kernel(const float* __restrict__ x,
           const float* __restrict__ cc,
           const float* __restrict__ alpha,
           const float* __restrict__ gamma,
           const float* __restrict__ beta,
           const float* __restrict__ thw,
           const float* __restrict__ thb,
           float* __restrict__ out)
{
    extern __shared__ char lds[];
    unsigned short* u = (unsigned short*)lds;          // [100][768] bf16
    float* S    = (float*)(lds + 153600);
    float* nrm  = (float*)(lds + 156672);
    float* dens = (float*)(lds + 157072);
    float* w2   = (float*)(lds + 157472);
    float* Wsh  = (float*)(lds + 157872);

    const int b   = blockIdx.x;
    const int tid = threadIdx.x;
    const int w   = tid >> 6;
    const int l   = tid & 63;
    const float* xb = x + (size_t)b * (NROW * (size_t)DDIM);

    // Preload gamma/beta for this lane's 12 columns (d = k*256 + 4*l + i)
    float4 gv[3], bv[3];
#pragma unroll
    for (int k = 0; k < 3; ++k) {
        gv[k] = *(const float4*)(gamma + k * 256 + 4 * l);
        bv[k] = *(const float4*)(beta  + k * 256 + 4 * l);
    }

    // ---------- Pass 1: LayerNorm each row, normalize, store u (bf16) ----------
    for (int n = w; n < NROW; n += NWAVE) {
        const float* xr = xb + (size_t)n * DDIM;
        float4 xv[3];
#pragma unroll
        for (int k = 0; k < 3; ++k)
            xv[k] = *(const float4*)(xr + k * 256 + 4 * l);

        float s = 0.f, sq = 0.f;
#pragma unroll
        for (int k = 0; k < 3; ++k) {
            const float* xp = (const float*)&xv[k];
#pragma unroll
            for (int i = 0; i < 4; ++i) { s += xp[i]; sq += xp[i] * xp[i]; }
        }
#pragma unroll
        for (int m = 32; m >= 1; m >>= 1) {
            s  += __shfl_xor(s,  m, 64);
            sq += __shfl_xor(sq, m, 64);
        }
        const float mu   = s * (1.0f / DDIM);
        const float var  = sq * (1.0f / DDIM) - mu * mu;
        const float rstd = rsqrtf(var + EPS_LN);

        float xn[12];
        float q = 0.f;
#pragma unroll
        for (int k = 0; k < 3; ++k) {
            const float* xp = (const float*)&xv[k];
            const float* gp = (const float*)&gv[k];
            const float* bp = (const float*)&bv[k];
#pragma unroll
            for (int i = 0; i < 4; ++i) {
                float v = (xp[i] - mu) * rstd * gp[i] + bp[i];
                xn[k * 4 + i] = v;
                q += v * v;
            }
        }
        q = wave_sum(q);
        const float nr  = sqrtf(q);
        const float inv = (nr > 0.f) ? (1.0f / nr) : 0.f;

        unsigned short* ur = u + n * DDIM;
#pragma unroll
        for (int k = 0; k < 3; ++k) {
            const int d0 = k * 256 + 4 * l;
#pragma unroll
            for (int i = 0; i < 4; ++i)
                ur[d0 + i] = f2bf(xn[k * 4 + i] * inv);
        }
        if (l == 0) nrm[n] = nr;
    }
    __syncthreads();

    // ---------- Pass S: S[d] = sum_n u[n][d] ----------
    if (tid < DDIM) {
        float acc = 0.f;
#pragma unroll 4
        for (int n = 0; n < NROW; ++n) acc += bf2f(u[n * DDIM + tid]);
        S[tid] = acc;
    }
    __syncthreads();

    // ---------- Pass 2a: density[n] = u_n . S ----------
    for (int n = w; n < NROW; n += NWAVE) {
        const unsigned short* ur = u + n * DDIM;
        float dot = 0.f;
#pragma unroll
        for (int k = 0; k < 3; ++k) {
            const int d0 = k * 256 + 4 * l;
#pragma unroll
            for (int i = 0; i < 4; ++i)
                dot += bf2f(ur[d0 + i]) * S[d0 + i];
        }
        dot = wave_sum(dot);
        if (l == 0) dens[n] = dot;
    }
    __syncthreads();

    // ---------- Pass 2b: min-max normalize, threshold, gate (wave 0) ----------
    if (w == 0) {
        const float va = dens[l];               // l in [0,64) < 100
        const bool  hb = (l < NROW - 64);       // 36 extra lanes
        const float vb = hb ? dens[64 + l] : 0.f;

        float mxv = hb ? fmaxf(va, vb) : va;
        float mnv = hb ? fminf(va, vb) : va;
#pragma unroll
        for (int m = 32; m >= 1; m >>= 1) {
            mxv = fmaxf(mxv, __shfl_xor(mxv, m, 64));
            mnv = fminf(mnv, __shfl_xor(mnv, m, 64));
        }
        const float rng = 1.0f / (mxv - mnv + EPSF);
        const float ra  = (va - mnv) * rng;
        const float rb  = (vb - mnv) * rng;

        float td = ra * thw[l] + (hb ? rb * thw[64 + l] : 0.f);
        td = wave_sum(td);
        const float z  = td + thb[0];
        const float th = alpha[0] / (1.0f + expf(-z));

        const float ga = fmaxf(ra - th, 0.f);
        const float gb = hb ? fmaxf(rb - th, 0.f) : 0.f;
        const float sg = wave_sum(ga + gb);
        const float wf = 1.0f / (sg + EPSF);

        w2[l] = ga * wf * nrm[l];
        if (hb) w2[64 + l] = gb * wf * nrm[64 + l];
        if (l == 0) Wsh[0] = sg * wf;   // W = sum(density_th)
    }
    __syncthreads();

    // ---------- Pass 3: out[d] = cc[d] + (sum_n w2[n]*u[n][d] - cc[d]*W)/N ----------
    if (tid < DDIM) {
        float acc = 0.f;
#pragma unroll 4
        for (int n = 0; n < NROW; ++n)
            acc += w2[n] * bf2f(u[n * DDIM + tid]);
        const float W = Wsh[0];
        const float c = cc[(size_t)b * DDIM + tid];
        out[(size_t)b * DDIM + tid] = c + (acc - c * W) * (1.0f / NROW);
    }
}

extern "C" void kernel_launch(void* const* d_in, const int* in_sizes, int n_in,
                              void* d_out, int out_size, void* d_ws, size_t ws_size,
                              hipStream_t stream) {
    const float* x     = (const float*)d_in[0];
    const float* cc    = (const float*)d_in[1];
    const float* alpha = (const float*)d_in[2];
    const float* gamma = (const float*)d_in[3];
    const float* beta  = (const float*)d_in[4];
    const float* thw   = (const float*)d_in[5];
    const float* thb   = (const float*)d_in[6];
    float* out = (float*)d_out;

    ccs_kernel<<<1024, BT, LDS_BYTES, stream>>>(x, cc, alpha, gamma, beta, thw, thb, out);
}